// Round 12
// baseline (1486.711 us; speedup 1.0000x reference)
//
#include <hip/hip_runtime.h>

#define NW 8         // waves per block
#define NTH 512      // 1 block/CU (LDS-bound); waves autonomous after one staging barrier

using f32x4 = __attribute__((ext_vector_type(4))) float;
using bf8   = __attribute__((ext_vector_type(8))) short;

__device__ __forceinline__ ushort f2bf(float f) {
    union { float f; unsigned u; } c{f};
    unsigned u = c.u;
    return (ushort)((u + 0x7fffu + ((u >> 16) & 1u)) >> 16);   // RTNE
}
// pure-C packed bf16 pair (no inline asm in the hot loop)
__device__ __forceinline__ unsigned pack2(float lo, float hi) {
    return (unsigned)f2bf(lo) | ((unsigned)f2bf(hi) << 16);
}

__device__ __forceinline__ bf8 mk_bf8(unsigned a, unsigned b, unsigned c, unsigned d) {
    uint4 q = make_uint4(a, b, c, d);
    return __builtin_bit_cast(bf8, q);
}

// async global->LDS, 16B/lane; LDS dest = wave-uniform base + lane*16 (HW semantics)
__device__ __forceinline__ void gload_lds16(const void* g, void* l) {
    __builtin_amdgcn_global_load_lds(
        (const __attribute__((address_space(1))) unsigned int*)g,
        (__attribute__((address_space(3))) unsigned int*)l, 16, 0, 0);
}

// ---------------- weight repack: f32 [K][N] -> bf16 A-fragment lines ----------------
// A-frag: lane l holds A[m=l&15][k=(l>>4)*8+j]. Line (nt*KS+ks) = 1 KB.
// Hidden layers use the register-chain feature permutation: k-slot (ks,grp,j) consumes
// f_in = (p>>1)*16 + grp*4 + (p&1)*2 + (j&1), p = ks*4 + (j>>1); p>=18 -> 0.
// Producer side: lane grp's output pair (nt,h) -> slot (p>>2, word p&3), p=2nt+h,
// lo=feature 16nt+4grp+2h, hi=+1. Verified on HW (R11 first-launch absmax 4.9e-4).
__global__ void repack_kernel(const float* __restrict__ Wstart,
                              const float* __restrict__ Wh0,
                              const float* __restrict__ Wh1,
                              const float* __restrict__ Wh2,
                              ushort* __restrict__ frag) {
    int i = blockIdx.x * blockDim.x + threadIdx.x;
    if (i < 4608) {                       // start: 9 lines, K=32, identity k-map
        int j = i & 7, l = (i >> 3) & 63, nt = i >> 9;
        int k = ((l >> 4) << 3) + j;
        int n = nt * 16 + (l & 15);
        frag[i] = f2bf(Wstart[k * 144 + n]);
    } else if (i < 73728) {               // hidden: 3 * 45 lines, permuted k-map
        int r = i - 4608;
        int h = r / 23040; r %= 23040;
        const float* W = (h == 0) ? Wh0 : ((h == 1) ? Wh1 : Wh2);
        int j = r & 7, l = (r >> 3) & 63, rem = r >> 9;
        int ks = rem % 5, nt = rem / 5;
        int grp_k = l >> 4;
        int p = ks * 4 + (j >> 1);
        int n = nt * 16 + (l & 15);
        float v = 0.0f;
        if (p < 18) {
            int f_in = (p >> 1) * 16 + grp_k * 4 + (p & 1) * 2 + (j & 1);
            v = W[f_in * 144 + n];
        }
        frag[i] = f2bf(v);
    }
}

// ---- one hidden layer, fully in registers; weights from LDS ----
__device__ __forceinline__ void hidden_reg(const ushort* __restrict__ wl,
                                           const float* __restrict__ bias,
                                           const unsigned (&xin)[2][5][4],
                                           unsigned (&xout)[2][5][4],
                                           int lane) {
    const int grp = lane >> 4;
    #pragma unroll
    for (int nt = 0; nt < 9; nt++) {
        bf8 wf[5];
        #pragma unroll
        for (int ks = 0; ks < 5; ks++)
            wf[ks] = *(const bf8*)&wl[((nt * 5 + ks) << 9) + (lane << 3)];
        float4 b4 = *(const float4*)&bias[nt * 16 + grp * 4];
        f32x4 a0, a1;
        a0[0] = b4.x; a0[1] = b4.y; a0[2] = b4.z; a0[3] = b4.w; a1 = a0;
        #pragma unroll
        for (int ks = 0; ks < 5; ks++) {
            a0 = __builtin_amdgcn_mfma_f32_16x16x32_bf16(
                     wf[ks], mk_bf8(xin[0][ks][0], xin[0][ks][1], xin[0][ks][2], xin[0][ks][3]), a0, 0, 0, 0);
            a1 = __builtin_amdgcn_mfma_f32_16x16x32_bf16(
                     wf[ks], mk_bf8(xin[1][ks][0], xin[1][ks][1], xin[1][ks][2], xin[1][ks][3]), a1, 0, 0, 0);
        }
        #pragma unroll
        for (int h = 0; h < 2; h++) {
            const int p_ = nt * 2 + h;
            xout[0][p_ >> 2][p_ & 3] = pack2(fmaxf(a0[2*h], 0.f), fmaxf(a0[2*h+1], 0.f));
            xout[1][p_ >> 2][p_ & 3] = pack2(fmaxf(a1[2*h], 0.f), fmaxf(a1[2*h+1], 0.f));
        }
    }
    xout[0][4][2] = 0; xout[0][4][3] = 0;   // zero-pad slots p=18,19
    xout[1][4][2] = 0; xout[1][4][3] = 0;
}

__global__ __launch_bounds__(NTH, 1)
void mlp_kernel(const float* __restrict__ score,
                const int* __restrict__ label_idx,
                const float* __restrict__ b_start,
                const float* __restrict__ b_h0,
                const float* __restrict__ b_h1,
                const float* __restrict__ b_h2,
                const float* __restrict__ W_end,
                const float* __restrict__ b_end,
                const ushort* __restrict__ frag,
                float* __restrict__ out, int E, int iters_total, int ipb) {
    __shared__ ushort wlds[73728];   // 147456 B: ALL repacked weights, block-resident
    const int tid  = threadIdx.x;
    const int lane = tid & 63;
    const int wave = tid >> 6;
    const int grp = lane >> 4, er = lane & 15;

    // stage 144 weight lines once: wave w -> lines 18w..18w+17
    for (int i = 0; i < 144 / NW; i++) {
        const int line = wave * (144 / NW) + i;
        gload_lds16(frag + (line << 9) + (lane << 3), &wlds[line << 9]);
    }
    // EXPLICIT drain: global_load_lds has no VGPR result; do not rely on the
    // compiler emitting vmcnt(0) before s_barrier (R10/R11 intermittent stale
    // weight lines = this race). Then barrier: all waves' DMAs complete.
    asm volatile("s_waitcnt vmcnt(0)" ::: "memory");
    __builtin_amdgcn_sched_barrier(0);
    __syncthreads();

    const ushort* wS = wlds;              // start: lines 0..8
    const ushort* w0 = wlds + 9  * 512;   // h0: 45 lines
    const ushort* w1 = wlds + 54 * 512;   // h1
    const ushort* w2 = wlds + 99 * 512;   // h2
    const float be = b_end[0];

    const int it_end = min(blockIdx.x * ipb + ipb, iters_total);
    for (int it = blockIdx.x * ipb + wave; it < it_end; it += NW) {
        const long e0 = (long)it << 5;    // 32 edges per iter, 2 MFMA tiles

        // ---- gather straight into B-frag registers (lane owns input slots 8grp..8grp+7) ----
        unsigned xg[2][4];
        #pragma unroll
        for (int t = 0; t < 2; t++) {
            const long e = e0 + t * 16 + er;
            const int4* ip = (const int4*)label_idx + e * 8 + grp * 2;
            int4 va{0,0,0,0}, vb{0,0,0,0};
            if (e < E) { va = ip[0]; vb = ip[1]; }
            xg[t][0] = pack2(score[va.x], score[va.y]);
            xg[t][1] = pack2(score[va.z], score[va.w]);
            xg[t][2] = pack2(score[vb.x], score[vb.y]);
            xg[t][3] = pack2(score[vb.z], score[vb.w]);
        }

        // ---- start layer (K=32) -> xa ----
        unsigned xa[2][5][4], xb[2][5][4];
        #pragma unroll
        for (int nt = 0; nt < 9; nt++) {
            bf8 wf = *(const bf8*)&wS[(nt << 9) + (lane << 3)];
            float4 b4 = *(const float4*)&b_start[nt * 16 + grp * 4];
            f32x4 a0, a1;
            a0[0] = b4.x; a0[1] = b4.y; a0[2] = b4.z; a0[3] = b4.w; a1 = a0;
            a0 = __builtin_amdgcn_mfma_f32_16x16x32_bf16(
                     wf, mk_bf8(xg[0][0], xg[0][1], xg[0][2], xg[0][3]), a0, 0, 0, 0);
            a1 = __builtin_amdgcn_mfma_f32_16x16x32_bf16(
                     wf, mk_bf8(xg[1][0], xg[1][1], xg[1][2], xg[1][3]), a1, 0, 0, 0);
            #pragma unroll
            for (int h = 0; h < 2; h++) {
                const int p_ = nt * 2 + h;
                xa[0][p_ >> 2][p_ & 3] = pack2(fmaxf(a0[2*h], 0.f), fmaxf(a0[2*h+1], 0.f));
                xa[1][p_ >> 2][p_ & 3] = pack2(fmaxf(a1[2*h], 0.f), fmaxf(a1[2*h+1], 0.f));
            }
        }
        xa[0][4][2] = 0; xa[0][4][3] = 0;
        xa[1][4][2] = 0; xa[1][4][3] = 0;

        hidden_reg(w0, b_h0, xa, xb, lane);
        hidden_reg(w1, b_h1, xb, xa, lane);

        // ---- final hidden layer fused with x @ W_end (f32, no bf16 round-trip) ----
        float part0 = 0.f, part1 = 0.f;
        #pragma unroll
        for (int nt = 0; nt < 9; nt++) {
            bf8 wf[5];
            #pragma unroll
            for (int ks = 0; ks < 5; ks++)
                wf[ks] = *(const bf8*)&w2[((nt * 5 + ks) << 9) + (lane << 3)];
            float4 b4 = *(const float4*)&b_h2[nt * 16 + grp * 4];
            f32x4 a0, a1;
            a0[0] = b4.x; a0[1] = b4.y; a0[2] = b4.z; a0[3] = b4.w; a1 = a0;
            #pragma unroll
            for (int ks = 0; ks < 5; ks++) {
                a0 = __builtin_amdgcn_mfma_f32_16x16x32_bf16(
                         wf[ks], mk_bf8(xa[0][ks][0], xa[0][ks][1], xa[0][ks][2], xa[0][ks][3]), a0, 0, 0, 0);
                a1 = __builtin_amdgcn_mfma_f32_16x16x32_bf16(
                         wf[ks], mk_bf8(xa[1][ks][0], xa[1][ks][1], xa[1][ks][2], xa[1][ks][3]), a1, 0, 0, 0);
            }
            float4 wv = *(const float4*)&W_end[nt * 16 + grp * 4];
            part0 += fmaxf(a0[0], 0.f) * wv.x + fmaxf(a0[1], 0.f) * wv.y
                   + fmaxf(a0[2], 0.f) * wv.z + fmaxf(a0[3], 0.f) * wv.w;
            part1 += fmaxf(a1[0], 0.f) * wv.x + fmaxf(a1[1], 0.f) * wv.y
                   + fmaxf(a1[2], 0.f) * wv.z + fmaxf(a1[3], 0.f) * wv.w;
        }
        part0 += __shfl_xor(part0, 16, 64); part0 += __shfl_xor(part0, 32, 64);
        part1 += __shfl_xor(part1, 16, 64); part1 += __shfl_xor(part1, 32, 64);
        if (lane < 16) {
            const long ea = e0 + lane, eb = e0 + 16 + lane;
            if (ea < E) out[ea] = be + part0;
            if (eb < E) out[eb] = be + part1;
        }
    }
}

extern "C" void kernel_launch(void* const* d_in, const int* in_sizes, int n_in,
                              void* d_out, int out_size, void* d_ws, size_t ws_size,
                              hipStream_t stream) {
    const float* score   = (const float*)d_in[0];
    const int*   lidx    = (const int*)  d_in[1];
    const float* W_start = (const float*)d_in[2];
    const float* b_start = (const float*)d_in[3];
    const float* W_h0    = (const float*)d_in[4];
    const float* b_h0    = (const float*)d_in[5];
    const float* W_h1    = (const float*)d_in[6];
    const float* b_h1    = (const float*)d_in[7];
    const float* W_h2    = (const float*)d_in[8];
    const float* b_h2    = (const float*)d_in[9];
    const float* W_end   = (const float*)d_in[10];
    const float* b_end   = (const float*)d_in[11];
    float* out = (float*)d_out;

    ushort* frag = (ushort*)d_ws;   // 73728 bf16 = 147456 B of repacked weights

    const int E = in_sizes[1] / 32;            // label_idx is [E][32]; in_sizes is FLAT count
    const int iters = (E + 31) / 32;
    const int G = 512;
    const int ipb = (iters + G - 1) / G;

    repack_kernel<<<288, 256, 0, stream>>>(W_start, W_h0, W_h1, W_h2, frag);

    mlp_kernel<<<G, NTH, 0, stream>>>(score, lidx, b_start, b_h0, b_h1, b_h2,
                                      W_end, b_end, frag, out, E, iters, ipb);
}

// Round 13
// 969.383 us; speedup vs baseline: 1.5337x; 1.5337x over previous
//
#include <hip/hip_runtime.h>

#define NTH 64       // one wave per block, persistent over tiles
#define STRIDE 168   // bf16 feature stride (336 B/row; proven 2-way-max bank behavior)

using f32x4 = __attribute__((ext_vector_type(4))) float;
using bf8   = __attribute__((ext_vector_type(8))) short;

__device__ __forceinline__ ushort f2bf(float f) {
    union { float f; unsigned u; } c{f};
    unsigned u = c.u;
    return (ushort)((u + 0x7fffu + ((u >> 16) & 1u)) >> 16);   // RTNE
}
__device__ __forceinline__ unsigned pack2(float lo, float hi) {
    return (unsigned)f2bf(lo) | ((unsigned)f2bf(hi) << 16);
}
__device__ __forceinline__ bf8 mk_bf8(unsigned a, unsigned b, unsigned c, unsigned d) {
    uint4 q = make_uint4(a, b, c, d);
    return __builtin_bit_cast(bf8, q);
}

// ---------------- weight repack: f32 [K][N] -> bf16 A-fragment lines (identity k-map) ----------------
// A-frag (mfma_f32_16x16x32_bf16): lane l holds A[m=l&15][k=(l>>4)*8+j], j=0..7
// frag[((nt*KS+ks)*64+l)*8+j]; m = nt*16+(l&15); k = ks*32+(l>>4)*8+j   [R5-proven]
__global__ void repack_kernel(const float* __restrict__ Wstart,
                              const float* __restrict__ Wh0,
                              const float* __restrict__ Wh1,
                              const float* __restrict__ Wh2,
                              ushort* __restrict__ frag) {
    int i = blockIdx.x * blockDim.x + threadIdx.x;
    if (i < 4608) {                       // start: 9 nt * 1 ks * 64 * 8
        int j = i & 7, l = (i >> 3) & 63, nt = i >> 9;
        int k = ((l >> 4) << 3) + j;
        int n = nt * 16 + (l & 15);
        frag[i] = f2bf(Wstart[k * 144 + n]);
    } else if (i < 73728) {               // hidden: 3 * (9 nt * 5 ks * 64 * 8)
        int r = i - 4608;
        int h = r / 23040; r %= 23040;
        const float* W = (h == 0) ? Wh0 : ((h == 1) ? Wh1 : Wh2);
        int j = r & 7, l = (r >> 3) & 63, rem = r >> 9;
        int ks = rem % 5, nt = rem / 5;
        int k = ks * 32 + ((l >> 4) << 3) + j;
        int n = nt * 16 + (l & 15);
        float v = (k < 144) ? W[k * 144 + n] : 0.0f;
        frag[i] = f2bf(v);
    }
}

// ---- hidden layer, in-place in this wave's private act tile (R5-proven pattern) ----
// xf read first (program order vs in-place writes, per-wave LDS ordering), wc/wn 1-deep wf prefetch.
template<bool FINAL>
__device__ __forceinline__ void hidden_layer(const ushort* __restrict__ wfrag,
                                             const float* __restrict__ bias,
                                             ushort (*act)[STRIDE],
                                             const float* __restrict__ W_end,
                                             float* part, int lane) {
    const int grp = lane >> 4, er = lane & 15;
    bf8 xf[4][5];
    #pragma unroll
    for (int t = 0; t < 4; t++)
        #pragma unroll
        for (int k = 0; k < 5; k++)
            xf[t][k] = *(const bf8*)&act[t * 16 + er][k * 32 + grp * 8];

    bf8 wc[5], wn[5];
    #pragma unroll
    for (int k = 0; k < 5; k++)
        wc[k] = *(const bf8*)&wfrag[((k << 6) + lane) << 3];

    #pragma unroll
    for (int nt = 0; nt < 9; nt++) {
        if (nt < 8) {
            #pragma unroll
            for (int k = 0; k < 5; k++)
                wn[k] = *(const bf8*)&wfrag[((((nt + 1) * 5 + k) << 6) + lane) << 3];
        }
        float4 b4 = *(const float4*)&bias[nt * 16 + grp * 4];
        f32x4 bv; bv[0] = b4.x; bv[1] = b4.y; bv[2] = b4.z; bv[3] = b4.w;
        f32x4 acc[4] = {bv, bv, bv, bv};
        #pragma unroll
        for (int k = 0; k < 5; k++)
            #pragma unroll
            for (int t = 0; t < 4; t++)
                acc[t] = __builtin_amdgcn_mfma_f32_16x16x32_bf16(wc[k], xf[t][k], acc[t], 0, 0, 0);

        if constexpr (FINAL) {
            float4 wv = *(const float4*)&W_end[nt * 16 + grp * 4];
            #pragma unroll
            for (int t = 0; t < 4; t++)
                part[t] += fmaxf(acc[t][0], 0.f) * wv.x + fmaxf(acc[t][1], 0.f) * wv.y
                         + fmaxf(acc[t][2], 0.f) * wv.z + fmaxf(acc[t][3], 0.f) * wv.w;
        } else {
            #pragma unroll
            for (int t = 0; t < 4; t++) {
                uint2 o;
                o.x = pack2(fmaxf(acc[t][0], 0.f), fmaxf(acc[t][1], 0.f));
                o.y = pack2(fmaxf(acc[t][2], 0.f), fmaxf(acc[t][3], 0.f));
                *(uint2*)&act[t * 16 + er][nt * 16 + grp * 4] = o;
            }
        }
        #pragma unroll
        for (int k = 0; k < 5; k++) wc[k] = wn[k];
    }
}

__global__ __launch_bounds__(NTH, 2)
void mlp_kernel(const float* __restrict__ score,
                const int* __restrict__ label_idx,
                const float* __restrict__ b_start,
                const float* __restrict__ b_h0,
                const float* __restrict__ b_h1,
                const float* __restrict__ b_h2,
                const float* __restrict__ W_end,
                const float* __restrict__ b_end,
                const ushort* __restrict__ frag,
                float* __restrict__ out, int E, int iters_total, int ipb) {
    __shared__ ushort act[64][STRIDE];
    const int lane = threadIdx.x;
    const int grp = lane >> 4, er = lane & 15;

    const int it0 = blockIdx.x * ipb;
    if (it0 >= iters_total) return;
    const int it_end = min(it0 + ipb, iters_total);

    // zero K-pad cols 144..159 once (hidden epilogues write only cols 0..143)
    {
        uint4 z = {0u, 0u, 0u, 0u};
        *(uint4*)&act[lane][144] = z;
        *(uint4*)&act[lane][152] = z;
    }

    const ushort* fS = frag;
    const ushort* f0 = frag + 4608;
    const ushort* f1 = frag + 4608 + 23040;
    const ushort* f2 = frag + 4608 + 46080;
    const float be = b_end[0];

    // prologue: idx loads for the first tile (lane owns edge er(+16t), feats grp*8..grp*8+7)
    int4 idxP[8];
    #pragma unroll
    for (int t = 0; t < 4; t++) {
        const long e = (long)it0 * 64 + t * 16 + er;
        const int4* ip = (const int4*)label_idx + e * 8 + grp * 2;
        idxP[2*t]   = (e < E) ? ip[0] : int4{0,0,0,0};
        idxP[2*t+1] = (e < E) ? ip[1] : int4{0,0,0,0};
    }

    for (int it = it0; it < it_end; ++it) {
        const long e0 = (long)it * 64;

        // ---- score gather for CURRENT tile (idx loaded a full tile ago -> latency hidden) ----
        unsigned xg[4][4];
        #pragma unroll
        for (int t = 0; t < 4; t++) {
            int4 va = idxP[2*t], vb = idxP[2*t+1];
            xg[t][0] = pack2(score[va.x], score[va.y]);
            xg[t][1] = pack2(score[va.z], score[va.w]);
            xg[t][2] = pack2(score[vb.x], score[vb.y]);
            xg[t][3] = pack2(score[vb.z], score[vb.w]);
        }

        // ---- prefetch idx for NEXT tile; ~6000 cyc of compute below to cover it ----
        {
            const long itn = (it + 1 < it_end) ? (it + 1) : it;
            #pragma unroll
            for (int t = 0; t < 4; t++) {
                const long e = itn * 64 + t * 16 + er;
                const int4* ip = (const int4*)label_idx + e * 8 + grp * 2;
                idxP[2*t]   = (e < E) ? ip[0] : int4{0,0,0,0};
                idxP[2*t+1] = (e < E) ? ip[1] : int4{0,0,0,0};
            }
        }

        // ---- start layer (K=32) straight from registers -> act LDS ----
        {
            bf8 wc = *(const bf8*)&fS[lane << 3];
            #pragma unroll
            for (int nt = 0; nt < 9; nt++) {
                bf8 wn;
                if (nt < 8) wn = *(const bf8*)&fS[(((nt + 1) << 6) + lane) << 3];
                float4 b4 = *(const float4*)&b_start[nt * 16 + grp * 4];
                f32x4 bv; bv[0] = b4.x; bv[1] = b4.y; bv[2] = b4.z; bv[3] = b4.w;
                f32x4 acc[4] = {bv, bv, bv, bv};
                #pragma unroll
                for (int t = 0; t < 4; t++)
                    acc[t] = __builtin_amdgcn_mfma_f32_16x16x32_bf16(
                                 wc, mk_bf8(xg[t][0], xg[t][1], xg[t][2], xg[t][3]), acc[t], 0, 0, 0);
                #pragma unroll
                for (int t = 0; t < 4; t++) {
                    uint2 o;
                    o.x = pack2(fmaxf(acc[t][0], 0.f), fmaxf(acc[t][1], 0.f));
                    o.y = pack2(fmaxf(acc[t][2], 0.f), fmaxf(acc[t][3], 0.f));
                    *(uint2*)&act[t * 16 + er][nt * 16 + grp * 4] = o;
                }
                wc = wn;
            }
        }

        // ---- hidden layers in-place; final fused with W_end ----
        float part[4] = {0.f, 0.f, 0.f, 0.f};
        hidden_layer<false>(f0, b_h0, act, nullptr, part, lane);
        hidden_layer<false>(f1, b_h1, act, nullptr, part, lane);
        hidden_layer<true >(f2, b_h2, act, W_end,  part, lane);

        #pragma unroll
        for (int t = 0; t < 4; t++) {
            part[t] += __shfl_xor(part[t], 16, 64);
            part[t] += __shfl_xor(part[t], 32, 64);
        }
        if (lane < 16) {
            #pragma unroll
            for (int t = 0; t < 4; t++) {
                const long e = e0 + t * 16 + lane;
                if (e < E) out[e] = be + part[t];
            }
        }
    }
}

extern "C" void kernel_launch(void* const* d_in, const int* in_sizes, int n_in,
                              void* d_out, int out_size, void* d_ws, size_t ws_size,
                              hipStream_t stream) {
    const float* score   = (const float*)d_in[0];
    const int*   lidx    = (const int*)  d_in[1];
    const float* W_start = (const float*)d_in[2];
    const float* b_start = (const float*)d_in[3];
    const float* W_h0    = (const float*)d_in[4];
    const float* b_h0    = (const float*)d_in[5];
    const float* W_h1    = (const float*)d_in[6];
    const float* b_h1    = (const float*)d_in[7];
    const float* W_h2    = (const float*)d_in[8];
    const float* b_h2    = (const float*)d_in[9];
    const float* W_end   = (const float*)d_in[10];
    const float* b_end   = (const float*)d_in[11];
    float* out = (float*)d_out;

    ushort* frag = (ushort*)d_ws;   // 73728 bf16 = 147456 B of repacked weights

    const int E = in_sizes[1] / 32;          // label_idx is [E][32]; in_sizes is FLAT count
    const int iters = (E + 63) / 64;
    const int G = 1792;                      // 7 one-wave blocks per CU (LDS-bound residency)
    const int ipb = (iters + G - 1) / G;

    repack_kernel<<<288, 256, 0, stream>>>(W_start, W_h0, W_h1, W_h2, frag);

    mlp_kernel<<<G, NTH, 0, stream>>>(score, lidx, b_start, b_h0, b_h1, b_h2,
                                      W_end, b_end, frag, out, E, iters, ipb);
}